// Round 5
// baseline (1803.390 us; speedup 1.0000x reference)
//
#include <hip/hip_runtime.h>
#include <hip/hip_bf16.h>
#include <hip/hip_cooperative_groups.h>
namespace cg = cooperative_groups;

#define DD 64
#define NBLK 256          // build grid: blocks (each owns an edge chunk / scan chunk)
#define MAXBUK 1024       // max buckets => supports n <= 131072 (problem: n = 100000)
#define BSHIFT 7          // 128 nodes per bucket

typedef __attribute__((ext_vector_type(8))) short short8v;  // 8 bf16 MFMA A/B frag
typedef __attribute__((ext_vector_type(4))) float f32x4;    // MFMA C/D frag

__device__ __forceinline__ unsigned pk_bf16(float a, float b) {
    __hip_bfloat162 h = __float22bfloat162_rn(make_float2(a, b));
    unsigned u; __builtin_memcpy(&u, &h, 4); return u;
}
__device__ __forceinline__ short f2bf_s(float f) {   // RNE scalar (startup only)
    union { float f; unsigned u; } x; x.f = f;
    unsigned r = x.u + 0x7fff + ((x.u >> 16) & 1);
    return (short)(r >> 16);
}
__device__ __forceinline__ float bf_lo(unsigned u) { return __int_as_float(u << 16); }
__device__ __forceinline__ float bf_hi(unsigned u) { return __int_as_float(u & 0xffff0000u); }
__device__ __forceinline__ short8v u4_to_s8(uint4 u) {
    union { uint4 u; short8v s; } x; x.u = u; return x.s;
}

// =====================================================================
// Build phases as __device__ fns — used by the single cooperative
// build_all kernel AND by discrete fallback wrappers (if coop launch
// is rejected). Zero global atomics anywhere.
// =====================================================================

// ---- scan pieces (exclusive scan of a[L] with NBLK chunks) ----
__device__ void scan_chunk(int* __restrict__ a, int* __restrict__ bs, int L, int* tmp) {
    int b = blockIdx.x, tid = threadIdx.x;
    int cpb = (L + NBLK - 1) / NBLK;
    int b0 = b * cpb, carry = 0;
    for (int r = 0; r < cpb; r += 256) {
        int i = b0 + r + tid;
        bool ok = (r + tid < cpb) && (i < L);
        int v = ok ? a[i] : 0;
        tmp[tid] = v; __syncthreads();
        for (int off = 1; off < 256; off <<= 1) {
            int t = (tid >= off) ? tmp[tid - off] : 0; __syncthreads();
            tmp[tid] += t; __syncthreads();
        }
        if (ok) a[i] = tmp[tid] - v + carry;
        carry += tmp[255];
        __syncthreads();
    }
    if (tid == 0) bs[b] = carry;
}
__device__ void scan_top(int* __restrict__ bs, int* tmp) {   // call with blockIdx==0 only
    int tid = threadIdx.x;
    int v = bs[tid];
    tmp[tid] = v; __syncthreads();
    for (int off = 1; off < 256; off <<= 1) {
        int t = (tid >= off) ? tmp[tid - off] : 0; __syncthreads();
        tmp[tid] += t; __syncthreads();
    }
    bs[tid] = tmp[tid] - v;
}
__device__ void scan_add(int* __restrict__ a, const int* __restrict__ bs, int L) {
    int b = blockIdx.x, tid = threadIdx.x;
    int cpb = (L + NBLK - 1) / NBLK;
    int b0 = b * cpb, base = bs[b];
    for (int r = tid; r < cpb; r += 256) {
        int i = b0 + r;
        if (i < L) a[i] += base;
    }
}

// ---- phase: per-(bucket,block) counts of dst and src streams ----
__device__ void ph_count(const int* __restrict__ src, const int* __restrict__ dst,
                         int* __restrict__ cnt, int E, int nbuk, int ce,
                         int* lA, int* lB) {
    int b = blockIdx.x, tid = threadIdx.x;
    for (int i = tid; i < MAXBUK; i += 256) { lA[i] = 0; lB[i] = 0; }
    __syncthreads();
    int e0 = b * ce, e1 = min(e0 + ce, E);
    for (int e = e0 + tid; e < e1; e += 256) {
        atomicAdd(&lA[dst[e] >> BSHIFT], 1);
        atomicAdd(&lB[src[e] >> BSHIFT], 1);
    }
    __syncthreads();
    int L2 = nbuk * NBLK;
    for (int i = tid; i < nbuk; i += 256) {
        cnt[i * NBLK + b]      = lA[i];
        cnt[L2 + i * NBLK + b] = lB[i];
    }
}

// ---- phase: scatter edges into bucket-partitioned order (LDS cursors) ----
__device__ void ph_pscat(const int* __restrict__ src, const int* __restrict__ dst,
                         const int* __restrict__ cnt,
                         unsigned int* __restrict__ partD, unsigned char* __restrict__ partS,
                         int E, int nbuk, int ce, int* lA, int* lB) {
    int b = blockIdx.x, tid = threadIdx.x;
    int L2 = nbuk * NBLK;
    for (int i = tid; i < nbuk; i += 256) {
        lA[i] = cnt[i * NBLK + b];
        lB[i] = cnt[L2 + i * NBLK + b] - E;
    }
    __syncthreads();
    int e0 = b * ce, e1 = min(e0 + ce, E);
    for (int e = e0 + tid; e < e1; e += 256) {
        int s = src[e], d = dst[e];
        int pd = atomicAdd(&lA[d >> BSHIFT], 1);
        partD[pd] = ((unsigned)(d & 127) << 17) | (unsigned)s;
        int ps = atomicAdd(&lB[s >> BSHIFT], 1);
        partS[ps] = (unsigned char)(s & 127);
    }
}

// ---- phase: per-bucket in/out-degree hist + degree-bin counts ----
__device__ void ph_histdeg(const unsigned int* __restrict__ partD,
                           const unsigned char* __restrict__ partS,
                           const int* __restrict__ cnt,
                           int* __restrict__ deg, int* __restrict__ outdeg,
                           int* __restrict__ cnt2, int E, int nbuk, int n,
                           int* lA, int* lB) {
    int tid = threadIdx.x;
    int L2 = nbuk * NBLK;
    for (int b2 = blockIdx.x; b2 < nbuk; b2 += gridDim.x) {
        if (tid < 128) { lA[tid] = 0; lA[128 + tid] = 0; }
        lB[tid] = 0;
        __syncthreads();
        int s0 = cnt[b2 * NBLK];
        int s1 = (b2 + 1 < nbuk) ? cnt[(b2 + 1) * NBLK] : E;
        for (int e = s0 + tid; e < s1; e += 256) atomicAdd(&lA[partD[e] >> 17], 1);
        int f0 = cnt[L2 + b2 * NBLK] - E;
        int f1 = (b2 + 1 < nbuk) ? cnt[L2 + (b2 + 1) * NBLK] - E : E;
        for (int e = f0 + tid; e < f1; e += 256) atomicAdd(&lA[128 + (int)partS[e]], 1);
        __syncthreads();
        if (tid < 128) {
            int v = (b2 << BSHIFT) + tid;
            if (v < n) {
                int di = lA[tid];
                deg[v] = di;
                outdeg[v] = lA[128 + tid];
                atomicAdd(&lB[min(di, 255)], 1);
            }
        }
        __syncthreads();
        cnt2[tid * nbuk + b2] = lB[tid];     // [bin][bucket] for flat scan
        __syncthreads();
    }
}

// ---- phase: degree-sort scatter + inverse perm + sorted-space arrays ----
__device__ void ph_dscat(const int* __restrict__ deg, const int* __restrict__ outdeg,
                         const int* __restrict__ cnt2,
                         int* __restrict__ perm, int* __restrict__ inv,
                         int* __restrict__ rowptr2, float* __restrict__ inn2,
                         float* __restrict__ outn2, float* __restrict__ rs2,
                         int nbuk, int n, int E, int* lB) {
    int tid = threadIdx.x;
    for (int b2 = blockIdx.x; b2 < nbuk; b2 += gridDim.x) {
        lB[tid] = cnt2[tid * nbuk + b2];
        __syncthreads();
        if (tid < 128) {
            int v = (b2 << BSHIFT) + tid;
            if (v < n) {
                int d = deg[v];
                int pos = atomicAdd(&lB[min(d, 255)], 1);
                perm[pos] = v;
                inv[v] = pos;
                rowptr2[pos] = d;                       // pre-scan degree
                inn2[pos] = rsqrtf((float)max(d, 1));
                float oc = (float)max(outdeg[v], 1);
                outn2[pos] = rsqrtf(oc);
                rs2[pos]   = sqrtf(oc);
            }
        }
        __syncthreads();
    }
    if (blockIdx.x == 0 && tid == 0) rowptr2[n] = E;    // untouched by length-n scan
}

// ---- phase: scatter esrc into sorted space, ids relabeled via inv ----
__device__ void ph_bscat(const unsigned int* __restrict__ partD,
                         const int* __restrict__ cnt,
                         const int* __restrict__ rowptr2, const int* __restrict__ inv,
                         int* __restrict__ esrc2, int E, int nbuk, int n, int* lA) {
    int tid = threadIdx.x;
    for (int b2 = blockIdx.x; b2 < nbuk; b2 += gridDim.x) {
        if (tid < 128) {
            int v = (b2 << BSHIFT) + tid;
            lA[tid] = (v < n) ? rowptr2[inv[v]] : 0;
        }
        __syncthreads();
        int s0 = cnt[b2 * NBLK];
        int s1 = (b2 + 1 < nbuk) ? cnt[(b2 + 1) * NBLK] : E;
        for (int e = s0 + tid; e < s1; e += 256) {
            unsigned u = partD[e];
            int p = atomicAdd(&lA[u >> 17], 1);
            esrc2[p] = inv[u & 0x1FFFFu];
        }
        __syncthreads();
    }
}

// ---- phase: hs[i] = feats[perm[i]] * outn2[i] (bf16 pack) ----
__device__ void ph_scale(const float* __restrict__ feats, const float* __restrict__ outn2,
                         const int* __restrict__ perm,
                         unsigned short* __restrict__ hs, int n) {
    int total = n * 8;
    for (int idx = blockIdx.x * 256 + (int)threadIdx.x; idx < total; idx += gridDim.x * 256) {
        int v = idx >> 3, c = idx & 7;
        int p = perm[v];
        float s = outn2[v];
        const float4* fp = (const float4*)(feats + (size_t)p * DD) + c * 2;
        float4 f0 = fp[0], f1 = fp[1];
        uint4 o;
        o.x = pk_bf16(f0.x * s, f0.y * s); o.y = pk_bf16(f0.z * s, f0.w * s);
        o.z = pk_bf16(f1.x * s, f1.y * s); o.w = pk_bf16(f1.z * s, f1.w * s);
        ((uint4*)hs)[idx] = o;
    }
}

// ============ single cooperative build kernel (R5) ============
__global__ __launch_bounds__(256) void build_all(
        const int* src, const int* dst, const float* feats,
        int* cnt, int* bsA, int* bsB, int* bsC,
        unsigned int* partD, unsigned char* partS,
        int* deg, int* outdeg, int* cnt2,
        int* perm, int* inv, int* rowptr2,
        float* inn2, float* outn2, float* rs2,
        int* esrc2, unsigned short* hs,
        int E, int n, int nbuk, int ce) {
    cg::grid_group grid = cg::this_grid();
    __shared__ int lA[MAXBUK], lB[MAXBUK], tmp[256];

    ph_count(src, dst, cnt, E, nbuk, ce, lA, lB);
    __threadfence(); grid.sync();

    scan_chunk(cnt, bsA, 2 * nbuk * NBLK, tmp);
    __threadfence(); grid.sync();
    if (blockIdx.x == 0) scan_top(bsA, tmp);
    __threadfence(); grid.sync();
    scan_add(cnt, bsA, 2 * nbuk * NBLK);
    __threadfence(); grid.sync();

    ph_pscat(src, dst, cnt, partD, partS, E, nbuk, ce, lA, lB);
    __threadfence(); grid.sync();

    ph_histdeg(partD, partS, cnt, deg, outdeg, cnt2, E, nbuk, n, lA, lB);
    __threadfence(); grid.sync();

    scan_chunk(cnt2, bsB, 256 * nbuk, tmp);
    __threadfence(); grid.sync();
    if (blockIdx.x == 0) scan_top(bsB, tmp);
    __threadfence(); grid.sync();
    scan_add(cnt2, bsB, 256 * nbuk);
    __threadfence(); grid.sync();

    ph_dscat(deg, outdeg, cnt2, perm, inv, rowptr2, inn2, outn2, rs2, nbuk, n, E, lB);
    __threadfence(); grid.sync();

    scan_chunk(rowptr2, bsC, n, tmp);
    __threadfence(); grid.sync();
    if (blockIdx.x == 0) scan_top(bsC, tmp);
    __threadfence(); grid.sync();
    scan_add(rowptr2, bsC, n);
    __threadfence(); grid.sync();

    ph_bscat(partD, cnt, rowptr2, inv, esrc2, E, nbuk, n, lA);
    __threadfence(); grid.sync();

    ph_scale(feats, outn2, perm, hs, n);
}

// ============ discrete fallback wrappers ============
__global__ __launch_bounds__(256) void k_count(const int* src, const int* dst, int* cnt,
                                               int E, int nbuk, int ce) {
    __shared__ int lA[MAXBUK], lB[MAXBUK];
    ph_count(src, dst, cnt, E, nbuk, ce, lA, lB);
}
__global__ void k_scan1(int* a, int* bs, int L) { __shared__ int tmp[256]; scan_chunk(a, bs, L, tmp); }
__global__ void k_scan2(int* bs) { __shared__ int tmp[256]; scan_top(bs, tmp); }
__global__ void k_scan3(int* a, const int* bs, int L) { scan_add(a, bs, L); }
__global__ __launch_bounds__(256) void k_pscat(const int* src, const int* dst, const int* cnt,
                                               unsigned int* partD, unsigned char* partS,
                                               int E, int nbuk, int ce) {
    __shared__ int lA[MAXBUK], lB[MAXBUK];
    ph_pscat(src, dst, cnt, partD, partS, E, nbuk, ce, lA, lB);
}
__global__ __launch_bounds__(256) void k_histdeg(const unsigned int* partD, const unsigned char* partS,
                                                 const int* cnt, int* deg, int* outdeg, int* cnt2,
                                                 int E, int nbuk, int n) {
    __shared__ int lA[MAXBUK], lB[MAXBUK];
    ph_histdeg(partD, partS, cnt, deg, outdeg, cnt2, E, nbuk, n, lA, lB);
}
__global__ __launch_bounds__(256) void k_dscat(const int* deg, const int* outdeg, const int* cnt2,
                                               int* perm, int* inv, int* rowptr2,
                                               float* inn2, float* outn2, float* rs2,
                                               int nbuk, int n, int E) {
    __shared__ int lB[MAXBUK];
    ph_dscat(deg, outdeg, cnt2, perm, inv, rowptr2, inn2, outn2, rs2, nbuk, n, E, lB);
}
__global__ __launch_bounds__(256) void k_bscat(const unsigned int* partD, const int* cnt,
                                               const int* rowptr2, const int* inv,
                                               int* esrc2, int E, int nbuk, int n) {
    __shared__ int lA[MAXBUK];
    ph_bscat(partD, cnt, rowptr2, inv, esrc2, E, nbuk, n, lA);
}
__global__ void k_scale(const float* feats, const float* outn2, const int* perm,
                        unsigned short* hs, int n) {
    ph_scale(feats, outn2, perm, hs, n);
}

// ============ fused 3-layer GCN kernel (cooperative; layers l0..l1-1) ========
// Body identical to the verified R3/R4 per-layer kernel; layer loop + grid
// sync moved inside. 1024 blocks = exactly 4/CU (LDS 34KB, VGPR<=128).
__global__ __launch_bounds__(256, 4) void gcn3_kernel(
    const int* __restrict__ rowptr, const int* __restrict__ esrc,
    const int* __restrict__ perm,
    const float* __restrict__ inn, const float* __restrict__ rs,
    const float* __restrict__ outn,
    unsigned short* __restrict__ hsA, unsigned short* __restrict__ hsB,
    const float* __restrict__ convW, const float* __restrict__ convB,
    const float* __restrict__ resW, const float* __restrict__ resB,
    const float* __restrict__ predW, const float* __restrict__ predB,
    const float* __restrict__ lnG, const float* __restrict__ lnBt,
    float* __restrict__ h_final, float* __restrict__ pred_out,
    int n, int l0, int l1)
{
    cg::grid_group grid = cg::this_grid();
    __shared__ __align__(16) short sWf[24 * 64 * 8];  // 24 A-frags (Wc|Wr|Wp) x 64 lanes x 8 bf16
    __shared__ __align__(16) short sXa[4][16 * 72];   // per-wave 16-node bf16 rows (72-short pad)
    __shared__ float sEps[4 * 64];                    // bias | ln_g | ln_b | pred_b

    int lane = threadIdx.x & 63;
    int wave = threadIdx.x >> 6;        // 0..3
    int q   = lane & 15;                // mfma: node id
    int gg  = lane >> 4;                // mfma: k/feat quad
    int q8  = lane & 7;                 // gather: 16B chunk (feats q8*8..+7)
    int o8  = lane >> 3;                // gather: node-in-half 0..7

    for (int l = l0; l < l1; ++l) {
        if (l > l0) { __threadfence(); grid.sync(); }

        const unsigned short* hs_in  = (l == 1) ? hsB : hsA;
        unsigned short*       hs_out = (l == 0) ? hsB : hsA;
        int first = (l == 0), last = (l == 2);
        const float* Wc = convW + (size_t)l * DD * DD;
        const float* Wr = resW  + (size_t)l * DD * DD;

        for (int idx = threadIdx.x; idx < 64; idx += blockDim.x) {
            sEps[idx]       = convB[l * DD + idx] + resB[l * DD + idx];
            sEps[64 + idx]  = lnG[l * DD + idx];
            sEps[128 + idx] = lnBt[l * DD + idx];
            sEps[192 + idx] = predB[idx];
        }
        // A-frags: f = mat*8 + ft*2 + kc ; elem j = W[kc*32+gg*8+j][ft*16+q]
        for (int f = wave * 6; f < wave * 6 + 6; ++f) {
            int mat = f >> 3, ft = (f >> 1) & 3, kc = f & 1;
            const float* Ws = (mat == 0) ? Wc : (mat == 1) ? Wr : predW;
            int feat = ft * 16 + q;
            int k0 = kc * 32 + gg * 8;
            short8v fr;
            #pragma unroll
            for (int j = 0; j < 8; ++j) fr[j] = f2bf_s(Ws[(k0 + j) * DD + feat]);
            *(short8v*)&sWf[(f * 64 + lane) * 8] = fr;
        }
        __syncthreads();

        short* xrow_w = &sXa[wave][0];
        const short8v* wf = (const short8v*)sWf;
        int wgid = blockIdx.x * 4 + wave;
        int nwav = gridDim.x * 4;
        int ngrp = (n + 15) >> 4;

        // LPT: descending group index = descending degree (sorted space)
        for (int g0 = wgid; g0 < ngrp; g0 += nwav) {
            int grp = ngrp - 1 - g0;
            int vbase = grp << 4;
            int vo = vbase + q;
            int vsel = min(vo, n - 1);

            // self row B-frags (raw bf16), issued early to overlap gather
            const uint4* hrow = (const uint4*)(hs_in + (size_t)vsel * DD);
            uint4 bh0u = hrow[gg];
            uint4 bh1u = hrow[4 + gg];
            float rsv  = rs[vsel];
            float innv = inn[vsel];

            // rowptr for the 16 nodes; per-lane start/deg for both halves
            int rp = rowptr[min(vbase + min(lane, 16), n)];
            int stA = __shfl(rp, o8);     int dgA = __shfl(rp, o8 + 1) - stA;
            int stB = __shfl(rp, o8 + 8); int dgB = __shfl(rp, o8 + 9) - stB;

            #pragma unroll
            for (int hh = 0; hh < 2; ++hh) {
                int st = hh ? stB : stA;
                int dg = hh ? dgB : dgA;
                int mdg = dg;
                mdg = max(mdg, __shfl_xor(mdg, 8));
                mdg = max(mdg, __shfl_xor(mdg, 16));
                mdg = max(mdg, __shfl_xor(mdg, 32));

                float a[8];
                #pragma unroll
                for (int c = 0; c < 8; ++c) a[c] = 0.0f;

                int id0 = (0 < dg) ? esrc[st + 0] : 0;  float m0 = (0 < dg) ? 1.f : 0.f;
                int id1 = (1 < dg) ? esrc[st + 1] : 0;  float m1 = (1 < dg) ? 1.f : 0.f;
                int id2 = (2 < dg) ? esrc[st + 2] : 0;  float m2 = (2 < dg) ? 1.f : 0.f;
                int id3 = (3 < dg) ? esrc[st + 3] : 0;  float m3 = (3 < dg) ? 1.f : 0.f;

                for (int t = 0; t < mdg; t += 4) {
                    uint4 r0 = *(const uint4*)(hs_in + (size_t)id0 * DD + q8 * 8);
                    uint4 r1 = *(const uint4*)(hs_in + (size_t)id1 * DD + q8 * 8);
                    uint4 r2 = *(const uint4*)(hs_in + (size_t)id2 * DD + q8 * 8);
                    uint4 r3 = *(const uint4*)(hs_in + (size_t)id3 * DD + q8 * 8);
                    float c0 = m0, c1 = m1, c2 = m2, c3 = m3;
                    int t4 = t + 4;
                    id0 = (t4 + 0 < dg) ? esrc[st + t4 + 0] : 0;  m0 = (t4 + 0 < dg) ? 1.f : 0.f;
                    id1 = (t4 + 1 < dg) ? esrc[st + t4 + 1] : 0;  m1 = (t4 + 1 < dg) ? 1.f : 0.f;
                    id2 = (t4 + 2 < dg) ? esrc[st + t4 + 2] : 0;  m2 = (t4 + 2 < dg) ? 1.f : 0.f;
                    id3 = (t4 + 3 < dg) ? esrc[st + t4 + 3] : 0;  m3 = (t4 + 3 < dg) ? 1.f : 0.f;
                    a[0] = fmaf(bf_lo(r0.x), c0, a[0]); a[1] = fmaf(bf_hi(r0.x), c0, a[1]);
                    a[2] = fmaf(bf_lo(r0.y), c0, a[2]); a[3] = fmaf(bf_hi(r0.y), c0, a[3]);
                    a[4] = fmaf(bf_lo(r0.z), c0, a[4]); a[5] = fmaf(bf_hi(r0.z), c0, a[5]);
                    a[6] = fmaf(bf_lo(r0.w), c0, a[6]); a[7] = fmaf(bf_hi(r0.w), c0, a[7]);
                    a[0] = fmaf(bf_lo(r1.x), c1, a[0]); a[1] = fmaf(bf_hi(r1.x), c1, a[1]);
                    a[2] = fmaf(bf_lo(r1.y), c1, a[2]); a[3] = fmaf(bf_hi(r1.y), c1, a[3]);
                    a[4] = fmaf(bf_lo(r1.z), c1, a[4]); a[5] = fmaf(bf_hi(r1.z), c1, a[5]);
                    a[6] = fmaf(bf_lo(r1.w), c1, a[6]); a[7] = fmaf(bf_hi(r1.w), c1, a[7]);
                    a[0] = fmaf(bf_lo(r2.x), c2, a[0]); a[1] = fmaf(bf_hi(r2.x), c2, a[1]);
                    a[2] = fmaf(bf_lo(r2.y), c2, a[2]); a[3] = fmaf(bf_hi(r2.y), c2, a[3]);
                    a[4] = fmaf(bf_lo(r2.z), c2, a[4]); a[5] = fmaf(bf_hi(r2.z), c2, a[5]);
                    a[6] = fmaf(bf_lo(r2.w), c2, a[6]); a[7] = fmaf(bf_hi(r2.w), c2, a[7]);
                    a[0] = fmaf(bf_lo(r3.x), c3, a[0]); a[1] = fmaf(bf_hi(r3.x), c3, a[1]);
                    a[2] = fmaf(bf_lo(r3.y), c3, a[2]); a[3] = fmaf(bf_hi(r3.y), c3, a[3]);
                    a[4] = fmaf(bf_lo(r3.z), c3, a[4]); a[5] = fmaf(bf_hi(r3.z), c3, a[5]);
                    a[6] = fmaf(bf_lo(r3.w), c3, a[6]); a[7] = fmaf(bf_hi(r3.w), c3, a[7]);
                }

                uint4 w4;
                w4.x = pk_bf16(a[0], a[1]); w4.y = pk_bf16(a[2], a[3]);
                w4.z = pk_bf16(a[4], a[5]); w4.w = pk_bf16(a[6], a[7]);
                *(uint4*)&xrow_w[(hh * 8 + o8) * 72 + q8 * 8] = w4;
            }

            // ---- B-frags + 16 MFMA (separate conv/res accumulators) ----
            const short* xr = &xrow_w[q * 72];
            short8v ba0 = *(const short8v*)&xr[gg * 8];
            short8v ba1 = *(const short8v*)&xr[32 + gg * 8];
            short8v sh0 = u4_to_s8(bh0u);
            short8v sh1 = u4_to_s8(bh1u);

            f32x4 accC[4], accR[4];
            #pragma unroll
            for (int ft = 0; ft < 4; ++ft) {
                f32x4 c = {0.f, 0.f, 0.f, 0.f};
                c = __builtin_amdgcn_mfma_f32_16x16x32_bf16(wf[(ft * 2 + 0) * 64 + lane], ba0, c, 0, 0, 0);
                c = __builtin_amdgcn_mfma_f32_16x16x32_bf16(wf[(ft * 2 + 1) * 64 + lane], ba1, c, 0, 0, 0);
                accC[ft] = c;
                f32x4 r = {0.f, 0.f, 0.f, 0.f};
                r = __builtin_amdgcn_mfma_f32_16x16x32_bf16(wf[(8 + ft * 2 + 0) * 64 + lane], sh0, r, 0, 0, 0);
                r = __builtin_amdgcn_mfma_f32_16x16x32_bf16(wf[(8 + ft * 2 + 1) * 64 + lane], sh1, r, 0, 0, 0);
                accR[ft] = r;
            }

            // ---- combine + LayerNorm + relu ----
            f32x4 ac[4];
            #pragma unroll
            for (int ft = 0; ft < 4; ++ft) {
                float4 b4 = *(const float4*)&sEps[ft * 16 + gg * 4];
                ac[ft][0] = fmaf(innv, accC[ft][0], fmaf(rsv, accR[ft][0], b4.x));
                ac[ft][1] = fmaf(innv, accC[ft][1], fmaf(rsv, accR[ft][1], b4.y));
                ac[ft][2] = fmaf(innv, accC[ft][2], fmaf(rsv, accR[ft][2], b4.z));
                ac[ft][3] = fmaf(innv, accC[ft][3], fmaf(rsv, accR[ft][3], b4.w));
            }
            float s = 0.f;
            #pragma unroll
            for (int ft = 0; ft < 4; ++ft) s += ac[ft][0] + ac[ft][1] + ac[ft][2] + ac[ft][3];
            s += __shfl_xor(s, 16); s += __shfl_xor(s, 32);
            float mu = s * (1.0f / 64.0f);
            float vsum = 0.f;
            #pragma unroll
            for (int ft = 0; ft < 4; ++ft) {
                #pragma unroll
                for (int r = 0; r < 4; ++r) { float d = ac[ft][r] - mu; vsum += d * d; }
            }
            vsum += __shfl_xor(vsum, 16); vsum += __shfl_xor(vsum, 32);
            float rinv = rsqrtf(vsum * (1.0f / 64.0f) + 1e-5f);

            float4 yv[4];
            #pragma unroll
            for (int ft = 0; ft < 4; ++ft) {
                float4 g4 = *(const float4*)&sEps[64 + ft * 16 + gg * 4];
                float4 c4 = *(const float4*)&sEps[128 + ft * 16 + gg * 4];
                yv[ft].x = fmaxf((ac[ft][0] - mu) * rinv * g4.x + c4.x, 0.f);
                yv[ft].y = fmaxf((ac[ft][1] - mu) * rinv * g4.y + c4.y, 0.f);
                yv[ft].z = fmaxf((ac[ft][2] - mu) * rinv * g4.z + c4.z, 0.f);
                yv[ft].w = fmaxf((ac[ft][3] - mu) * rinv * g4.w + c4.w, 0.f);
            }

            if (!last) {
                if (vo < n) {
                    float on = outn[vo];
                    #pragma unroll
                    for (int ft = 0; ft < 4; ++ft) {
                        size_t off = (size_t)vo * DD + ft * 16 + gg * 4;
                        uint2 p;
                        p.x = pk_bf16(yv[ft].x * on, yv[ft].y * on);
                        p.y = pk_bf16(yv[ft].z * on, yv[ft].w * on);
                        *(uint2*)&hs_out[off] = p;
                        if (first) {
                            *(float4*)&h_final[off] = yv[ft];
                        } else {
                            float4 hf = *(const float4*)&h_final[off];
                            hf.x += yv[ft].x; hf.y += yv[ft].y;
                            hf.z += yv[ft].z; hf.w += yv[ft].w;
                            *(float4*)&h_final[off] = hf;
                        }
                    }
                }
            } else {
                // fused prediction -> scatter full row to pred_out[perm[v]]
                int pvo = perm[vsel];
                #pragma unroll
                for (int ft = 0; ft < 4; ++ft) {
                    float4 hf = make_float4(0.f, 0.f, 0.f, 0.f);
                    if (vo < n) {
                        float4 old = *(const float4*)&h_final[(size_t)vo * DD + ft * 16 + gg * 4];
                        hf.x = old.x + yv[ft].x; hf.y = old.y + yv[ft].y;
                        hf.z = old.z + yv[ft].z; hf.w = old.w + yv[ft].w;
                    }
                    uint2 p;
                    p.x = pk_bf16(hf.x, hf.y);
                    p.y = pk_bf16(hf.z, hf.w);
                    *(uint2*)&xrow_w[q * 72 + ft * 16 + gg * 4] = p;   // same-wave DS, in order
                }
                short8v bp0 = *(const short8v*)&xr[gg * 8];
                short8v bp1 = *(const short8v*)&xr[32 + gg * 8];
                #pragma unroll
                for (int ft = 0; ft < 4; ++ft) {
                    f32x4 p = {0.f, 0.f, 0.f, 0.f};
                    p = __builtin_amdgcn_mfma_f32_16x16x32_bf16(wf[(16 + ft * 2 + 0) * 64 + lane], bp0, p, 0, 0, 0);
                    p = __builtin_amdgcn_mfma_f32_16x16x32_bf16(wf[(16 + ft * 2 + 1) * 64 + lane], bp1, p, 0, 0, 0);
                    if (vo < n) {
                        float4 b4 = *(const float4*)&sEps[192 + ft * 16 + gg * 4];
                        float4 o = make_float4(p[0] + b4.x, p[1] + b4.y, p[2] + b4.z, p[3] + b4.w);
                        *(float4*)&pred_out[(size_t)pvo * DD + ft * 16 + gg * 4] = o;
                    }
                }
            }
        }
        // need LDS (sWf/sEps) stable until all waves of this block finish the layer
        __syncthreads();
    }
}

extern "C" void kernel_launch(void* const* d_in, const int* in_sizes, int n_in,
                              void* d_out, int out_size, void* d_ws, size_t ws_size,
                              hipStream_t stream) {
    const float* feats  = (const float*)d_in[0];
    const int*   src    = (const int*)d_in[1];
    const int*   dst    = (const int*)d_in[2];
    const float* conv_W = (const float*)d_in[3];
    const float* conv_b = (const float*)d_in[4];
    const float* res_W  = (const float*)d_in[5];
    const float* res_b  = (const float*)d_in[6];
    const float* ln_g   = (const float*)d_in[7];
    const float* ln_b   = (const float*)d_in[8];
    const float* pred_W = (const float*)d_in[9];
    const float* pred_b = (const float*)d_in[10];

    int N = in_sizes[0] / DD;
    int E = in_sizes[1];

    int nbuk = (N + (1 << BSHIFT) - 1) >> BSHIFT;        // 782
    int ce   = (E + NBLK - 1) / NBLK;

    // ---- workspace layout ----
    int*   rowptr2 = (int*)d_ws;                         // N+1 (sorted space)
    int*   cnt    = rowptr2 + (N + 1);                   // MAXBUK*NBLK*2 (2 MB)
    int*   bsA    = cnt + MAXBUK * NBLK * 2;             // 1024
    int*   bsB    = bsA + 1024;                          // 1024
    int*   bsC    = bsB + 1024;                          // 1024
    int*   esrc2  = bsC + 1024;                          // E (sorted space)
    float* outn2  = (float*)(esrc2 + E);                 // N
    float* inn2   = outn2 + N;                           // N
    float* rs2    = inn2 + N;                            // N
    int*   perm   = (int*)(rs2 + N);                     // N (needed by gcn L3)
    float* base   = (float*)(((uintptr_t)(perm + N) + 15) & ~(uintptr_t)15);
    unsigned short* hsA = (unsigned short*)base;                     // N*64 bf16
    unsigned short* hsB = (unsigned short*)(base + (size_t)N * 32);  // N*64 bf16
    float* hfin  = base + (size_t)N * 64;                // N*64 fp32 (sorted space)
    // build-only aliases:
    unsigned int*  partD = (unsigned int*)hfin;                      // E uints (on hfin)
    unsigned char* partS = (unsigned char*)(partD + E);              // E bytes
    int* cnt2   = (int*)hsB;                             // 256*nbuk (on hsB)
    int* deg    = cnt2 + 256 * MAXBUK;                   // N
    int* outdeg = deg + N;                               // N
    int* inv    = outdeg + N;                            // N

    // ---- build: one cooperative kernel; fallback to discrete chain ----
    {
        void* args[] = {
            (void*)&src, (void*)&dst, (void*)&feats,
            (void*)&cnt, (void*)&bsA, (void*)&bsB, (void*)&bsC,
            (void*)&partD, (void*)&partS,
            (void*)&deg, (void*)&outdeg, (void*)&cnt2,
            (void*)&perm, (void*)&inv, (void*)&rowptr2,
            (void*)&inn2, (void*)&outn2, (void*)&rs2,
            (void*)&esrc2, (void*)&hsA,
            (void*)&E, (void*)&N, (void*)&nbuk, (void*)&ce };
        hipError_t err = hipLaunchCooperativeKernel(
            (const void*)build_all, dim3(NBLK), dim3(256), args, 0, stream);
        if (err != hipSuccess) {
            (void)hipGetLastError();   // clear sticky error
            k_count  <<<NBLK, 256, 0, stream>>>(src, dst, cnt, E, nbuk, ce);
            k_scan1  <<<NBLK, 256, 0, stream>>>(cnt, bsA, 2 * nbuk * NBLK);
            k_scan2  <<<1, 256, 0, stream>>>(bsA);
            k_scan3  <<<NBLK, 256, 0, stream>>>(cnt, bsA, 2 * nbuk * NBLK);
            k_pscat  <<<NBLK, 256, 0, stream>>>(src, dst, cnt, partD, partS, E, nbuk, ce);
            k_histdeg<<<NBLK, 256, 0, stream>>>(partD, partS, cnt, deg, outdeg, cnt2, E, nbuk, N);
            k_scan1  <<<NBLK, 256, 0, stream>>>(cnt2, bsB, 256 * nbuk);
            k_scan2  <<<1, 256, 0, stream>>>(bsB);
            k_scan3  <<<NBLK, 256, 0, stream>>>(cnt2, bsB, 256 * nbuk);
            k_dscat  <<<NBLK, 256, 0, stream>>>(deg, outdeg, cnt2, perm, inv, rowptr2,
                                                inn2, outn2, rs2, nbuk, N, E);
            k_scan1  <<<NBLK, 256, 0, stream>>>(rowptr2, bsC, N);
            k_scan2  <<<1, 256, 0, stream>>>(bsC);
            k_scan3  <<<NBLK, 256, 0, stream>>>(rowptr2, bsC, N);
            k_bscat  <<<NBLK, 256, 0, stream>>>(partD, cnt, rowptr2, inv, esrc2, E, nbuk, N);
            k_scale  <<<NBLK, 256, 0, stream>>>(feats, outn2, perm, hsA, N);
        }
    }

    // ---- 3 layers: one cooperative kernel; fallback to 3 launches ----
    {
        float* pred_out = (float*)d_out;
        int l0 = 0, l1 = 3;
        void* args[] = {
            (void*)&rowptr2, (void*)&esrc2, (void*)&perm,
            (void*)&inn2, (void*)&rs2, (void*)&outn2,
            (void*)&hsA, (void*)&hsB,
            (void*)&conv_W, (void*)&conv_b, (void*)&res_W, (void*)&res_b,
            (void*)&pred_W, (void*)&pred_b, (void*)&ln_g, (void*)&ln_b,
            (void*)&hfin, (void*)&pred_out,
            (void*)&N, (void*)&l0, (void*)&l1 };
        hipError_t err = hipLaunchCooperativeKernel(
            (const void*)gcn3_kernel, dim3(1024), dim3(256), args, 0, stream);
        if (err != hipSuccess) {
            (void)hipGetLastError();   // clear sticky error
            for (int l = 0; l < 3; ++l) {
                gcn3_kernel<<<1024, 256, 0, stream>>>(
                    rowptr2, esrc2, perm, inn2, rs2, outn2, hsA, hsB,
                    conv_W, conv_b, res_W, res_b, pred_W, pred_b, ln_g, ln_b,
                    hfin, (float*)d_out, N, l, l + 1);
            }
        }
    }
}

// Round 6
// 297.122 us; speedup vs baseline: 6.0695x; 6.0695x over previous
//
#include <hip/hip_runtime.h>
#include <hip/hip_bf16.h>

#define DD 64
#define NBLK 128          // partition pass blocks (each owns a contiguous edge chunk)
#define MAXBUK 1024       // max buckets => supports n <= 131072 (problem: n = 100000)
#define BSHIFT 7          // 128 nodes per bucket

typedef __attribute__((ext_vector_type(8))) short short8v;  // 8 bf16 MFMA A/B frag
typedef __attribute__((ext_vector_type(4))) float f32x4;    // MFMA C/D frag

__device__ __forceinline__ unsigned pk_bf16(float a, float b) {
    __hip_bfloat162 h = __float22bfloat162_rn(make_float2(a, b));
    unsigned u; __builtin_memcpy(&u, &h, 4); return u;
}
__device__ __forceinline__ short f2bf_s(float f) {   // RNE scalar (startup only)
    union { float f; unsigned u; } x; x.f = f;
    unsigned r = x.u + 0x7fff + ((x.u >> 16) & 1);
    return (short)(r >> 16);
}
__device__ __forceinline__ float bf_lo(unsigned u) { return __int_as_float(u << 16); }
__device__ __forceinline__ float bf_hi(unsigned u) { return __int_as_float(u & 0xffff0000u); }
__device__ __forceinline__ short8v u4_to_s8(uint4 u) {
    union { uint4 u; short8v s; } x; x.u = u; return x.s;
}
// 2-phase scan: final offset = blockwise-exclusive + block base (no scan3 pass)
__device__ __forceinline__ int ofs_at(const int* __restrict__ c,
                                      const int* __restrict__ bs, int i) {
    return c[i] + bs[i >> 8];
}

// =====================================================================
// CSR build, original node space — zero global atomics, 6 dispatches.
// (R6: reverted from degree-sort/coop experiments; R2/R4/R5 lessons:
//  perm indirection 2x FETCH; edge_sort useless for random graphs;
//  grid.sync ~58us each; min-waves launch_bounds => spills.)
// =====================================================================

__global__ __launch_bounds__(256) void part_count(
        const int* __restrict__ src, const int* __restrict__ dst,
        int* __restrict__ cnt, int E, int nbuk, int ce) {
    __shared__ int hd[MAXBUK], hs[MAXBUK];
    for (int i = threadIdx.x; i < MAXBUK; i += 256) { hd[i] = 0; hs[i] = 0; }
    __syncthreads();
    int e0 = blockIdx.x * ce;
    int e1 = min(e0 + ce, E);
    for (int e = e0 + (int)threadIdx.x; e < e1; e += 256) {
        atomicAdd(&hd[dst[e] >> BSHIFT], 1);
        atomicAdd(&hs[src[e] >> BSHIFT], 1);
    }
    __syncthreads();
    int L2 = nbuk * NBLK;
    // [bucket][block] layout -> flat exclusive scan yields global offsets
    for (int b = threadIdx.x; b < nbuk; b += 256) {
        cnt[b * NBLK + blockIdx.x]      = hd[b];
        cnt[L2 + b * NBLK + blockIdx.x] = hs[b];
    }
}

__global__ void scan1p(int* __restrict__ a, int* __restrict__ bsums, int L) {
    __shared__ int tmp[256];
    int gid = blockIdx.x * 256 + threadIdx.x;
    int v = (gid < L) ? a[gid] : 0;
    tmp[threadIdx.x] = v;
    __syncthreads();
    for (int off = 1; off < 256; off <<= 1) {
        int t = (threadIdx.x >= off) ? tmp[threadIdx.x - off] : 0;
        __syncthreads();
        tmp[threadIdx.x] += t;
        __syncthreads();
    }
    if (gid < L) a[gid] = tmp[threadIdx.x] - v;
    if (threadIdx.x == 255) bsums[blockIdx.x] = tmp[255];
}
__global__ void scan2p(int* __restrict__ bsums, int nb) {
    __shared__ int tmp[1024];
    int v = (threadIdx.x < (unsigned)nb) ? bsums[threadIdx.x] : 0;
    tmp[threadIdx.x] = v;
    __syncthreads();
    for (int off = 1; off < 1024; off <<= 1) {
        int t = (threadIdx.x >= off) ? tmp[threadIdx.x - off] : 0;
        __syncthreads();
        tmp[threadIdx.x] += t;
        __syncthreads();
    }
    if (threadIdx.x < (unsigned)nb) bsums[threadIdx.x] = tmp[threadIdx.x] - v;
}

__global__ __launch_bounds__(256) void part_scatter(
        const int* __restrict__ src, const int* __restrict__ dst,
        const int* __restrict__ cnt, const int* __restrict__ bsA,
        unsigned int* __restrict__ partD, unsigned char* __restrict__ partS,
        int E, int nbuk, int ce) {
    __shared__ int cd[MAXBUK], cs[MAXBUK];
    int L2 = nbuk * NBLK;
    for (int b = threadIdx.x; b < nbuk; b += 256) {
        cd[b] = ofs_at(cnt, bsA, b * NBLK + blockIdx.x);
        cs[b] = ofs_at(cnt, bsA, L2 + b * NBLK + blockIdx.x) - E;
    }
    __syncthreads();
    int e0 = blockIdx.x * ce;
    int e1 = min(e0 + ce, E);
    for (int e = e0 + (int)threadIdx.x; e < e1; e += 256) {
        int s = src[e], d = dst[e];
        int pd = atomicAdd(&cd[d >> BSHIFT], 1);
        partD[pd] = ((unsigned)(d & 127) << 17) | (unsigned)s;
        int ps = atomicAdd(&cs[s >> BSHIFT], 1);
        partS[ps] = (unsigned char)(s & 127);
    }
}

// ---- fused per-bucket finalize: in-hist -> rowptr/inn + esrc scatter,
//      out-hist -> outn/rs. One kernel replaces bucket_csr + bucket_deg. ----
__global__ __launch_bounds__(256) void bucket_all(
        const unsigned int* __restrict__ partD, const unsigned char* __restrict__ partS,
        const int* __restrict__ cnt, const int* __restrict__ bsA,
        int* __restrict__ rowptr, int* __restrict__ esrc,
        float* __restrict__ inn, float* __restrict__ outn, float* __restrict__ rs,
        int E, int nbuk, int n) {
    __shared__ int hi[128], sc[128], cu[128], ho[128];
    int b = blockIdx.x, tid = threadIdx.x;
    int L2 = nbuk * NBLK;
    int e0 = ofs_at(cnt, bsA, b * NBLK);
    int e1 = (b + 1 < nbuk) ? ofs_at(cnt, bsA, (b + 1) * NBLK) : E;
    int f0 = ofs_at(cnt, bsA, L2 + b * NBLK) - E;
    int f1 = (b + 1 < nbuk) ? ofs_at(cnt, bsA, L2 + (b + 1) * NBLK) - E : E;
    if (tid < 128) { hi[tid] = 0; ho[tid] = 0; }
    __syncthreads();
    for (int e = e0 + tid; e < e1; e += 256) atomicAdd(&hi[partD[e] >> 17], 1);
    for (int e = f0 + tid; e < f1; e += 256) atomicAdd(&ho[(int)partS[e]], 1);
    __syncthreads();
    if (tid < 128) sc[tid] = hi[tid];
    __syncthreads();
    for (int off = 1; off < 128; off <<= 1) {
        int t = (tid < 128 && tid >= off) ? sc[tid - off] : 0;
        __syncthreads();
        if (tid < 128) sc[tid] += t;
        __syncthreads();
    }
    if (tid < 128) {
        int excl = e0 + sc[tid] - hi[tid];
        cu[tid] = excl;
        int v = (b << BSHIFT) + tid;
        if (v < n) {
            rowptr[v] = excl;
            inn[v] = rsqrtf((float)max(hi[tid], 1));
            float oc = (float)max(ho[tid], 1);
            outn[v] = rsqrtf(oc);
            rs[v]   = sqrtf(oc);
        }
    }
    if (b == 0 && tid == 0) rowptr[n] = E;
    __syncthreads();
    for (int e = e0 + tid; e < e1; e += 256) {
        unsigned u = partD[e];
        int p = atomicAdd(&cu[u >> 17], 1);
        esrc[p] = (int)(u & 0x1FFFFu);
    }
}

// ---------------- pre-scale: hs(bf16) = feats * outn ----------------
__global__ void scale_kernel(const float* __restrict__ feats, const float* __restrict__ outn,
                             unsigned short* __restrict__ hs, int n) {
    int idx = blockIdx.x * blockDim.x + threadIdx.x;   // one uint4 (8 feats) per thread
    if (idx < n * 8) {
        int v = idx >> 3;
        float s = outn[v];
        const float4* fp = (const float4*)feats + (size_t)idx * 2;
        float4 f0 = fp[0], f1 = fp[1];
        uint4 o;
        o.x = pk_bf16(f0.x * s, f0.y * s); o.y = pk_bf16(f0.z * s, f0.w * s);
        o.z = pk_bf16(f1.x * s, f1.y * s); o.w = pk_bf16(f1.z * s, f1.w * s);
        ((uint4*)hs)[idx] = o;
    }
}

// ---------------- fused per-layer kernel (verified R1 body, unchanged) ------
__global__ __launch_bounds__(256) void gcn_kernel(
    const int* __restrict__ rowptr, const int* __restrict__ esrc,
    const float* __restrict__ inn, const float* __restrict__ rs,
    const float* __restrict__ outn,
    const unsigned short* __restrict__ hs_in,
    const float* __restrict__ Wc, const float* __restrict__ bc,
    const float* __restrict__ Wr, const float* __restrict__ br,
    const float* __restrict__ Wp, const float* __restrict__ pb,
    const float* __restrict__ g, const float* __restrict__ bb,
    unsigned short* __restrict__ hs_out, float* __restrict__ h_final,
    float* __restrict__ pred_out,
    int first, int last, int n)
{
    __shared__ __align__(16) short sWf[24 * 64 * 8];  // 24 A-frags (Wc|Wr|Wp) x 64 lanes x 8 bf16
    __shared__ __align__(16) short sXa[4][16 * 72];   // per-wave 16-node bf16 rows (72-short pad)
    __shared__ float sEps[4 * 64];                    // bias | ln_g | ln_b | pred_b

    int lane = threadIdx.x & 63;
    int wave = threadIdx.x >> 6;        // 0..3
    int q   = lane & 15;                // mfma: node id
    int gg  = lane >> 4;                // mfma: k/feat quad
    int q8  = lane & 7;                 // gather: 16B chunk (feats q8*8..+7)
    int o8  = lane >> 3;                // gather: node-in-half 0..7

    for (int idx = threadIdx.x; idx < 64; idx += blockDim.x) {
        sEps[idx]       = bc[idx] + br[idx];
        sEps[64 + idx]  = g[idx];
        sEps[128 + idx] = bb[idx];
        sEps[192 + idx] = pb[idx];
    }
    // A-frags: f = mat*8 + ft*2 + kc ; elem j = W[kc*32+gg*8+j][ft*16+q]
    for (int f = wave * 6; f < wave * 6 + 6; ++f) {
        int mat = f >> 3, ft = (f >> 1) & 3, kc = f & 1;
        const float* Ws = (mat == 0) ? Wc : (mat == 1) ? Wr : Wp;
        int feat = ft * 16 + q;
        int k0 = kc * 32 + gg * 8;
        short8v fr;
        #pragma unroll
        for (int j = 0; j < 8; ++j) fr[j] = f2bf_s(Ws[(k0 + j) * DD + feat]);
        *(short8v*)&sWf[(f * 64 + lane) * 8] = fr;
    }
    __syncthreads();

    short* xrow_w = &sXa[wave][0];
    const short8v* wf = (const short8v*)sWf;
    int wgid = blockIdx.x * 4 + wave;
    int nwav = gridDim.x * 4;
    int ngrp = (n + 15) >> 4;

    for (int grp = wgid; grp < ngrp; grp += nwav) {
        int vbase = grp << 4;
        int vo = vbase + q;
        int vsel = min(vo, n - 1);

        // self row B-frags (raw bf16), issued early to overlap gather
        const uint4* hrow = (const uint4*)(hs_in + (size_t)vsel * DD);
        uint4 bh0u = hrow[gg];
        uint4 bh1u = hrow[4 + gg];
        float rsv  = rs[vsel];
        float innv = inn[vsel];

        // rowptr for the 16 nodes; per-lane start/deg for both halves
        int rp = rowptr[min(vbase + min(lane, 16), n)];
        int stA = __shfl(rp, o8);     int dgA = __shfl(rp, o8 + 1) - stA;
        int stB = __shfl(rp, o8 + 8); int dgB = __shfl(rp, o8 + 9) - stB;

        #pragma unroll
        for (int hh = 0; hh < 2; ++hh) {
            int st = hh ? stB : stA;
            int dg = hh ? dgB : dgA;
            // wave-uniform max degree over this half's 8 nodes
            int mdg = dg;
            mdg = max(mdg, __shfl_xor(mdg, 8));
            mdg = max(mdg, __shfl_xor(mdg, 16));
            mdg = max(mdg, __shfl_xor(mdg, 32));

            float a[8];
            #pragma unroll
            for (int c = 0; c < 8; ++c) a[c] = 0.0f;

            int id0 = (0 < dg) ? esrc[st + 0] : 0;  float m0 = (0 < dg) ? 1.f : 0.f;
            int id1 = (1 < dg) ? esrc[st + 1] : 0;  float m1 = (1 < dg) ? 1.f : 0.f;
            int id2 = (2 < dg) ? esrc[st + 2] : 0;  float m2 = (2 < dg) ? 1.f : 0.f;
            int id3 = (3 < dg) ? esrc[st + 3] : 0;  float m3 = (3 < dg) ? 1.f : 0.f;

            for (int t = 0; t < mdg; t += 4) {
                // 4 independent 16B row-chunk loads (wave: 4 x 1KB coalesced)
                uint4 r0 = *(const uint4*)(hs_in + (size_t)id0 * DD + q8 * 8);
                uint4 r1 = *(const uint4*)(hs_in + (size_t)id1 * DD + q8 * 8);
                uint4 r2 = *(const uint4*)(hs_in + (size_t)id2 * DD + q8 * 8);
                uint4 r3 = *(const uint4*)(hs_in + (size_t)id3 * DD + q8 * 8);
                float c0 = m0, c1 = m1, c2 = m2, c3 = m3;
                // prefetch next 4 edge indices (overlap row loads)
                int t4 = t + 4;
                id0 = (t4 + 0 < dg) ? esrc[st + t4 + 0] : 0;  m0 = (t4 + 0 < dg) ? 1.f : 0.f;
                id1 = (t4 + 1 < dg) ? esrc[st + t4 + 1] : 0;  m1 = (t4 + 1 < dg) ? 1.f : 0.f;
                id2 = (t4 + 2 < dg) ? esrc[st + t4 + 2] : 0;  m2 = (t4 + 2 < dg) ? 1.f : 0.f;
                id3 = (t4 + 3 < dg) ? esrc[st + t4 + 3] : 0;  m3 = (t4 + 3 < dg) ? 1.f : 0.f;
                // accumulate
                a[0] = fmaf(bf_lo(r0.x), c0, a[0]); a[1] = fmaf(bf_hi(r0.x), c0, a[1]);
                a[2] = fmaf(bf_lo(r0.y), c0, a[2]); a[3] = fmaf(bf_hi(r0.y), c0, a[3]);
                a[4] = fmaf(bf_lo(r0.z), c0, a[4]); a[5] = fmaf(bf_hi(r0.z), c0, a[5]);
                a[6] = fmaf(bf_lo(r0.w), c0, a[6]); a[7] = fmaf(bf_hi(r0.w), c0, a[7]);
                a[0] = fmaf(bf_lo(r1.x), c1, a[0]); a[1] = fmaf(bf_hi(r1.x), c1, a[1]);
                a[2] = fmaf(bf_lo(r1.y), c1, a[2]); a[3] = fmaf(bf_hi(r1.y), c1, a[3]);
                a[4] = fmaf(bf_lo(r1.z), c1, a[4]); a[5] = fmaf(bf_hi(r1.z), c1, a[5]);
                a[6] = fmaf(bf_lo(r1.w), c1, a[6]); a[7] = fmaf(bf_hi(r1.w), c1, a[7]);
                a[0] = fmaf(bf_lo(r2.x), c2, a[0]); a[1] = fmaf(bf_hi(r2.x), c2, a[1]);
                a[2] = fmaf(bf_lo(r2.y), c2, a[2]); a[3] = fmaf(bf_hi(r2.y), c2, a[3]);
                a[4] = fmaf(bf_lo(r2.z), c2, a[4]); a[5] = fmaf(bf_hi(r2.z), c2, a[5]);
                a[6] = fmaf(bf_lo(r2.w), c2, a[6]); a[7] = fmaf(bf_hi(r2.w), c2, a[7]);
                a[0] = fmaf(bf_lo(r3.x), c3, a[0]); a[1] = fmaf(bf_hi(r3.x), c3, a[1]);
                a[2] = fmaf(bf_lo(r3.y), c3, a[2]); a[3] = fmaf(bf_hi(r3.y), c3, a[3]);
                a[4] = fmaf(bf_lo(r3.z), c3, a[4]); a[5] = fmaf(bf_hi(r3.z), c3, a[5]);
                a[6] = fmaf(bf_lo(r3.w), c3, a[6]); a[7] = fmaf(bf_hi(r3.w), c3, a[7]);
            }

            // lane holds its node-chunk's final raw sums; pack + one LDS write
            uint4 w4;
            w4.x = pk_bf16(a[0], a[1]); w4.y = pk_bf16(a[2], a[3]);
            w4.z = pk_bf16(a[4], a[5]); w4.w = pk_bf16(a[6], a[7]);
            *(uint4*)&xrow_w[(hh * 8 + o8) * 72 + q8 * 8] = w4;
        }

        // ---- B-frags + 16 MFMA (separate conv/res accumulators) ----
        const short* xr = &xrow_w[q * 72];
        short8v ba0 = *(const short8v*)&xr[gg * 8];
        short8v ba1 = *(const short8v*)&xr[32 + gg * 8];
        short8v sh0 = u4_to_s8(bh0u);
        short8v sh1 = u4_to_s8(bh1u);

        f32x4 accC[4], accR[4];
        #pragma unroll
        for (int ft = 0; ft < 4; ++ft) {
            f32x4 c = {0.f, 0.f, 0.f, 0.f};
            c = __builtin_amdgcn_mfma_f32_16x16x32_bf16(wf[(ft * 2 + 0) * 64 + lane], ba0, c, 0, 0, 0);
            c = __builtin_amdgcn_mfma_f32_16x16x32_bf16(wf[(ft * 2 + 1) * 64 + lane], ba1, c, 0, 0, 0);
            accC[ft] = c;
            f32x4 r = {0.f, 0.f, 0.f, 0.f};
            r = __builtin_amdgcn_mfma_f32_16x16x32_bf16(wf[(8 + ft * 2 + 0) * 64 + lane], sh0, r, 0, 0, 0);
            r = __builtin_amdgcn_mfma_f32_16x16x32_bf16(wf[(8 + ft * 2 + 1) * 64 + lane], sh1, r, 0, 0, 0);
            accR[ft] = r;
        }

        // ---- combine (inn*conv + rs*res + bias) + LayerNorm + relu ----
        f32x4 ac[4];
        #pragma unroll
        for (int ft = 0; ft < 4; ++ft) {
            float4 b4 = *(const float4*)&sEps[ft * 16 + gg * 4];
            ac[ft][0] = fmaf(innv, accC[ft][0], fmaf(rsv, accR[ft][0], b4.x));
            ac[ft][1] = fmaf(innv, accC[ft][1], fmaf(rsv, accR[ft][1], b4.y));
            ac[ft][2] = fmaf(innv, accC[ft][2], fmaf(rsv, accR[ft][2], b4.z));
            ac[ft][3] = fmaf(innv, accC[ft][3], fmaf(rsv, accR[ft][3], b4.w));
        }
        float s = 0.f;
        #pragma unroll
        for (int ft = 0; ft < 4; ++ft) s += ac[ft][0] + ac[ft][1] + ac[ft][2] + ac[ft][3];
        s += __shfl_xor(s, 16); s += __shfl_xor(s, 32);
        float mu = s * (1.0f / 64.0f);
        float vsum = 0.f;
        #pragma unroll
        for (int ft = 0; ft < 4; ++ft) {
            #pragma unroll
            for (int r = 0; r < 4; ++r) { float d = ac[ft][r] - mu; vsum += d * d; }
        }
        vsum += __shfl_xor(vsum, 16); vsum += __shfl_xor(vsum, 32);
        float rinv = rsqrtf(vsum * (1.0f / 64.0f) + 1e-5f);

        float4 yv[4];
        #pragma unroll
        for (int ft = 0; ft < 4; ++ft) {
            float4 g4 = *(const float4*)&sEps[64 + ft * 16 + gg * 4];
            float4 c4 = *(const float4*)&sEps[128 + ft * 16 + gg * 4];
            yv[ft].x = fmaxf((ac[ft][0] - mu) * rinv * g4.x + c4.x, 0.f);
            yv[ft].y = fmaxf((ac[ft][1] - mu) * rinv * g4.y + c4.y, 0.f);
            yv[ft].z = fmaxf((ac[ft][2] - mu) * rinv * g4.z + c4.z, 0.f);
            yv[ft].w = fmaxf((ac[ft][3] - mu) * rinv * g4.w + c4.w, 0.f);
        }

        if (!last) {
            if (vo < n) {
                float on = outn[vo];
                #pragma unroll
                for (int ft = 0; ft < 4; ++ft) {
                    size_t off = (size_t)vo * DD + ft * 16 + gg * 4;
                    uint2 p;
                    p.x = pk_bf16(yv[ft].x * on, yv[ft].y * on);
                    p.y = pk_bf16(yv[ft].z * on, yv[ft].w * on);
                    *(uint2*)&hs_out[off] = p;
                    if (first) {
                        *(float4*)&h_final[off] = yv[ft];
                    } else {
                        float4 hf = *(const float4*)&h_final[off];
                        hf.x += yv[ft].x; hf.y += yv[ft].y;
                        hf.z += yv[ft].z; hf.w += yv[ft].w;
                        *(float4*)&h_final[off] = hf;
                    }
                }
            }
        } else {
            // fused prediction: hf = h_final + y -> LDS (bf16) -> B-frags -> 8 MFMA -> d_out
            #pragma unroll
            for (int ft = 0; ft < 4; ++ft) {
                float4 hf = make_float4(0.f, 0.f, 0.f, 0.f);
                if (vo < n) {
                    float4 old = *(const float4*)&h_final[(size_t)vo * DD + ft * 16 + gg * 4];
                    hf.x = old.x + yv[ft].x; hf.y = old.y + yv[ft].y;
                    hf.z = old.z + yv[ft].z; hf.w = old.w + yv[ft].w;
                }
                uint2 p;
                p.x = pk_bf16(hf.x, hf.y);
                p.y = pk_bf16(hf.z, hf.w);
                *(uint2*)&xrow_w[q * 72 + ft * 16 + gg * 4] = p;   // same-wave DS, in order
            }
            short8v bp0 = *(const short8v*)&xr[gg * 8];
            short8v bp1 = *(const short8v*)&xr[32 + gg * 8];
            #pragma unroll
            for (int ft = 0; ft < 4; ++ft) {
                f32x4 p = {0.f, 0.f, 0.f, 0.f};
                p = __builtin_amdgcn_mfma_f32_16x16x32_bf16(wf[(16 + ft * 2 + 0) * 64 + lane], bp0, p, 0, 0, 0);
                p = __builtin_amdgcn_mfma_f32_16x16x32_bf16(wf[(16 + ft * 2 + 1) * 64 + lane], bp1, p, 0, 0, 0);
                if (vo < n) {
                    float4 b4 = *(const float4*)&sEps[192 + ft * 16 + gg * 4];
                    float4 o = make_float4(p[0] + b4.x, p[1] + b4.y, p[2] + b4.z, p[3] + b4.w);
                    *(float4*)&pred_out[(size_t)vo * DD + ft * 16 + gg * 4] = o;
                }
            }
        }
    }
}

extern "C" void kernel_launch(void* const* d_in, const int* in_sizes, int n_in,
                              void* d_out, int out_size, void* d_ws, size_t ws_size,
                              hipStream_t stream) {
    const float* feats  = (const float*)d_in[0];
    const int*   src    = (const int*)d_in[1];
    const int*   dst    = (const int*)d_in[2];
    const float* conv_W = (const float*)d_in[3];
    const float* conv_b = (const float*)d_in[4];
    const float* res_W  = (const float*)d_in[5];
    const float* res_b  = (const float*)d_in[6];
    const float* ln_g   = (const float*)d_in[7];
    const float* ln_b   = (const float*)d_in[8];
    const float* pred_W = (const float*)d_in[9];
    const float* pred_b = (const float*)d_in[10];

    int N = in_sizes[0] / DD;
    int E = in_sizes[1];

    int nbuk = (N + (1 << BSHIFT) - 1) >> BSHIFT;        // 782
    int ce   = (E + NBLK - 1) / NBLK;
    int L    = nbuk * NBLK * 2;                          // 200192
    int nb   = (L + 255) / 256;                          // 783 (<=1024 for scan2p)

    // ---- workspace layout (~58 MB) ----
    int*   rowptr = (int*)d_ws;                          // N+1
    int*   cnt    = rowptr + (N + 1);                    // MAXBUK*NBLK*2 (1 MB)
    int*   bsA    = cnt + MAXBUK * NBLK * 2;             // 1024
    int*   esrc   = bsA + 1024;                          // E
    float* outn   = (float*)(esrc + E);                  // N
    float* inn    = outn + N;                            // N
    float* rs     = inn + N;                             // N
    float* base   = (float*)(((uintptr_t)(rs + N) + 15) & ~(uintptr_t)15);
    unsigned short* hsA = (unsigned short*)base;                     // N*64 bf16
    unsigned short* hsB = (unsigned short*)(base + (size_t)N * 32);  // N*64 bf16
    float* hfin  = base + (size_t)N * 64;                // N*64 fp32
    // partition scratch aliases hfin (dead before layer-0 writes hfin)
    unsigned int*  partD = (unsigned int*)hfin;                      // E uints
    unsigned char* partS = (unsigned char*)(partD + E);              // E bytes

    part_count  <<<NBLK, 256, 0, stream>>>(src, dst, cnt, E, nbuk, ce);
    scan1p      <<<nb, 256, 0, stream>>>(cnt, bsA, L);
    scan2p      <<<1, 1024, 0, stream>>>(bsA, nb);
    part_scatter<<<NBLK, 256, 0, stream>>>(src, dst, cnt, bsA, partD, partS, E, nbuk, ce);
    bucket_all  <<<nbuk, 256, 0, stream>>>(partD, partS, cnt, bsA, rowptr, esrc,
                                           inn, outn, rs, E, nbuk, N);
    scale_kernel<<<(N * 8 + 255) / 256, 256, 0, stream>>>(feats, outn, hsA, N);

    // L1: hsA->hsB ; L2: hsB->hsA ; L3: hsA->(pred d_out), hs_out unused
    const unsigned short* ins[3]  = {hsA, hsB, hsA};
    unsigned short*       outs[3] = {hsB, hsA, hsB};
    for (int l = 0; l < 3; ++l) {
        gcn_kernel<<<1024, 256, 0, stream>>>(
            rowptr, esrc, inn, rs, outn, ins[l],
            conv_W + (size_t)l * DD * DD, conv_b + (size_t)l * DD,
            res_W  + (size_t)l * DD * DD, res_b  + (size_t)l * DD,
            pred_W, pred_b,
            ln_g   + (size_t)l * DD,      ln_b   + (size_t)l * DD,
            outs[l], hfin, (float*)d_out,
            (l == 0) ? 1 : 0, (l == 2) ? 1 : 0, N);
    }
}